// Round 10
// baseline (43.812 us; speedup 1.0000x reference)
//
#include <hip/hip_runtime.h>
#include <hip/hip_fp16.h>
#include <math.h>

#define BB 16
#define CC 3
#define HH 512
#define WW 512
#define HW (HH * WW)
#define RAD 5
#define SEGV 8
#define NSEG (HH / SEGV)            // 64 segments per image
#define NSTRIP 5                    // 5 overlapping 128-col strips, 116 valid each
#define STRIPW 116
#define NTASK (BB * NSEG * NSTRIP)  // 5120 wave-tasks -> 5 waves/SIMD
#define NBLK (NTASK / 2)            // 2560 blocks (2 waves each)
#define NITER (SEGV + 2 * RAD)      // 18 row iterations

__device__ __forceinline__ __half2 shfl_h2(__half2 v, int src) {
    union { __half2 h; int i; } u;
    u.h = v;
    u.i = __shfl(u.i, src);
    return u.h;
}

// R7 body verbatim; only task granularity changed (SEGV 16 -> 8) to double
// occupancy (2.5 -> 5 waves/SIMD). Horizontal 11-sum: {dot,pp} packed half2
// tree + tt f32 tree (12 shuffles/iter). Vertical: 11-deep half2 register
// ring with exact-cancellation f32 running sums. No LDS/barriers in loop.
__global__ __launch_bounds__(128) void fused_shfl(
    const float* __restrict__ pred, const float* __restrict__ target,
    float* __restrict__ ws_sq, float* __restrict__ ws_cos)
{
    __shared__ float red[4];
    const int tid  = threadIdx.x;
    const int wave = tid >> 6, lane = tid & 63;

    // bijective XCD-contiguous swizzle (2560 % 8 == 0)
    const int bid = (int)blockIdx.x;
    const int swz = (bid & 7) * (NBLK / 8) + (bid >> 3);

    const int task  = swz * 2 + wave;
    const int img   = task / (NSEG * NSTRIP);
    const int rem   = task % (NSEG * NSTRIP);
    const int seg   = rem / NSTRIP;
    const int strip = rem - seg * NSTRIP;

    const int y0   = seg * SEGV;
    const int col0 = strip * STRIPW - 6 + lane * 2;      // even
    const int colc = min(max(col0, 0), WW - 2);
    const float mx = (col0 >= 0 && col0 < WW) ? 1.f : 0.f;
    const bool vout = (lane >= 3) && (lane <= 60) && (col0 < WW);

    const long base = (long)img * (CC * HW);

    // prefetch row 0 (issue-early)
    float2 P0, P1, P2, T0, T1, T2;
    {
        const int y  = y0 - RAD;
        const int yc = y < 0 ? 0 : y;
        const long off = base + (long)yc * WW + colc;
        P0 = *(const float2*)(pred + off);
        P1 = *(const float2*)(pred + off + HW);
        P2 = *(const float2*)(pred + off + 2 * HW);
        T0 = *(const float2*)(target + off);
        T1 = *(const float2*)(target + off + HW);
        T2 = *(const float2*)(target + off + 2 * HW);
    }

    __half2 ring0[11], ring1[11], ringT[11];   // (hd0,hp0), (hd1,hp1), (ht0,ht1)
    float Sd0=0.f, Sd1=0.f, Sp0=0.f, Sp1=0.f, St0=0.f, St1=0.f;
    float sq = 0.f, cosacc = 0.f;

    #pragma unroll
    for (int it = 0; it < NITER; ++it) {
        const int y = y0 - RAD + it;
        const float msk = (y >= 0 && y < HH) ? mx : 0.f;

        const float2 p0=P0, p1=P1, p2=P2, t0=T0, t1=T1, t2=T2;
        if (it + 1 < NITER) {                     // prefetch next row
            const int y2  = y0 - RAD + it + 1;
            const int yc2 = min(max(y2, 0), HH - 1);
            const long off2 = base + (long)yc2 * WW + colc;
            P0 = *(const float2*)(pred + off2);
            P1 = *(const float2*)(pred + off2 + HW);
            P2 = *(const float2*)(pred + off2 + 2 * HW);
            T0 = *(const float2*)(target + off2);
            T1 = *(const float2*)(target + off2 + HW);
            T2 = *(const float2*)(target + off2 + 2 * HW);
        }

        // per-pixel dot/pp/tt, masked (zero padding outside image)
        const float ad = (p0.x*t0.x + p1.x*t1.x + p2.x*t2.x) * msk;
        const float bd = (p0.y*t0.y + p1.y*t1.y + p2.y*t2.y) * msk;
        const float ap = (p0.x*p0.x + p1.x*p1.x + p2.x*p2.x) * msk;
        const float bp = (p0.y*p0.y + p1.y*p1.y + p2.y*p2.y) * msk;
        const float at = (t0.x*t0.x + t1.x*t1.x + t2.x*t2.x) * msk;
        const float bt = (t0.y*t0.y + t1.y*t1.y + t2.y*t2.y) * msk;

        // PSNR squared error: owned rows x valid cols only
        if (it >= RAD && it < RAD + SEGV && vout) {
            const float e0=p0.x-t0.x, e1=p1.x-t1.x, e2=p2.x-t2.x;
            const float f0=p0.y-t0.y, f1=p1.y-t1.y, f2=p2.y-t2.y;
            sq += e0*e0 + e1*e1 + e2*e2 + f0*f0 + f1*f1 + f2*f2;
        }

        // ---- horizontal 11-window ----
        __half2 h0dp, h1dp;
        {
            const __half2 Pk = __floats2half2_rn(ad + bd, ap + bp);
            const __half2 Ak = __floats2half2_rn(ad, ap);
            const __half2 Bk = __floats2half2_rn(bd, bp);
            const __half2 u1 = __hadd2(Pk, shfl_h2(Pk, lane + 1));
            const __half2 u2 = __hadd2(u1, shfl_h2(u1, lane + 2));
            const __half2 u3 = __hadd2(u2, shfl_h2(Pk, lane + 4));
            const __half2 S5 = shfl_h2(u3, lane - 2);
            h0dp = __hadd2(shfl_h2(Bk, lane - 3), S5);
            h1dp = __hadd2(S5, shfl_h2(Ak, lane + 3));
        }
        __half2 hT;
        {
            const float pr = at + bt;
            const float u1 = pr + __shfl(pr, lane + 1);
            const float u2 = u1 + __shfl(u1, lane + 2);
            const float u3 = u2 + __shfl(pr, lane + 4);
            const float S5 = __shfl(u3, lane - 2);
            hT = __floats2half2_rn(__shfl(bt, lane - 3) + S5,
                                   S5 + __shfl(at, lane + 3));
        }

        // accumulate the QUANTIZED values -> ring subtract cancels exactly
        const float2 f0 = __half22float2(h0dp);
        const float2 f1 = __half22float2(h1dp);
        const float2 fT = __half22float2(hT);
        Sd0 += f0.x; Sp0 += f0.y;
        Sd1 += f1.x; Sp1 += f1.y;
        St0 += fT.x; St1 += fT.y;

        if (it >= 10) {
            if (vout) {
                cosacc += Sd0 / (sqrtf(fmaxf(Sp0 * St0, 0.f)) + 1e-6f);
                cosacc += Sd1 / (sqrtf(fmaxf(Sp1 * St1, 0.f)) + 1e-6f);
            }
            const float2 o0 = __half22float2(ring0[(it + 1) % 11]);
            const float2 o1 = __half22float2(ring1[(it + 1) % 11]);
            const float2 oT = __half22float2(ringT[(it + 1) % 11]);
            Sd0 -= o0.x; Sp0 -= o0.y;
            Sd1 -= o1.x; Sp1 -= o1.y;
            St0 -= oT.x; St1 -= oT.y;
        }
        ring0[it % 11] = h0dp;
        ring1[it % 11] = h1dp;
        ringT[it % 11] = hT;
    }

    // wave reduce -> block partials
    #pragma unroll
    for (int o = 32; o > 0; o >>= 1) {
        cosacc += __shfl_down(cosacc, o);
        sq     += __shfl_down(sq, o);
    }
    if (lane == 0) { red[wave] = cosacc; red[wave + 2] = sq; }
    __syncthreads();
    if (tid == 0) {
        ws_cos[swz] = red[0] + red[1];
        ws_sq [swz] = red[2] + red[3];
    }
}

// ---------------- finalize: 2560 sq + 2560 cos partials ----------------
__global__ __launch_bounds__(256) void finalize5(
    const float* __restrict__ ws_sq, const float* __restrict__ ws_cos,
    float* __restrict__ out)
{
    __shared__ float sq_b[16];
    __shared__ float cred[4];
    const int tid = threadIdx.x;

    // sq: 160 partials per image; 16 threads/image, 10 values each
    const int b = tid >> 4, j = tid & 15;
    float s = 0.f;
    #pragma unroll
    for (int k = 0; k < 10; ++k) s += ws_sq[b * 160 + j * 10 + k];
    #pragma unroll
    for (int o = 8; o > 0; o >>= 1) s += __shfl_down(s, o, 16);
    if (j == 0) sq_b[b] = s;

    float c = 0.f;
    #pragma unroll
    for (int k = 0; k < 10; ++k) c += ws_cos[tid + 256 * k];
    #pragma unroll
    for (int o = 32; o > 0; o >>= 1) c += __shfl_down(c, o);
    if ((tid & 63) == 0) cred[tid >> 6] = c;
    __syncthreads();

    if (tid == 0) {
        const float csum = cred[0] + cred[1] + cred[2] + cred[3];
        const float scale = 4.342944819032518f;   // 10 / ln(10)
        float lsum = 0.f;
        for (int bb = 0; bb < 16; ++bb)
            lsum += logf(sq_b[bb] / (float)(CC * HW) + 1e-8f);
        out[0] = scale * (lsum / (float)BB) + (1.f - csum / (float)(BB * HW));
    }
}

extern "C" void kernel_launch(void* const* d_in, const int* in_sizes, int n_in,
                              void* d_out, int out_size, void* d_ws, size_t ws_size,
                              hipStream_t stream)
{
    const float* pred   = (const float*)d_in[0];
    const float* target = (const float*)d_in[1];

    float* ws_sq  = (float*)d_ws;                        // 2560 floats
    float* ws_cos = (float*)((char*)d_ws + 12288);       // 2560 floats

    fused_shfl<<<dim3(NBLK), 128, 0, stream>>>(pred, target, ws_sq, ws_cos);
    finalize5<<<1, 256, 0, stream>>>(ws_sq, ws_cos, (float*)d_out);
}

// Round 11
// 36.366 us; speedup vs baseline: 1.2047x; 1.2047x over previous
//
#include <hip/hip_runtime.h>
#include <hip/hip_fp16.h>
#include <math.h>

#define BB 16
#define CC 3
#define HH 512
#define WW 512
#define HW (HH * WW)
#define RAD 5
#define SEGV 16
#define NSEG (HH / SEGV)            // 32 segments per image
#define NSTRIP 5                    // 5 overlapping 128-col strips, 116 valid each
#define STRIPW 116
#define NTASK (BB * NSEG * NSTRIP)  // 2560 wave-tasks
#define NBLK (NTASK / 2)            // 1280 blocks (2 waves each)
#define NITER (SEGV + 2 * RAD)      // 26 row iterations

__device__ __forceinline__ __half2 shfl_h2(__half2 v, int src) {
    union { __half2 h; int i; } u;
    u.h = v;
    u.i = __shfl(u.i, src);
    return u.h;
}

// R7 structure with depth-2 load pipeline: rotating triple of register row
// buffers (static it%3 indexing under full unroll -> no scratch, no copies).
// Horizontal 11-sum: {dot,pp} packed half2 shuffle tree + tt f32 tree.
// Vertical: 11-deep half2 ring, exact-cancellation f32 running sums.
// No LDS/barriers in the main loop.
__global__ __launch_bounds__(128) void fused_shfl(
    const float* __restrict__ pred, const float* __restrict__ target,
    float* __restrict__ ws_sq, float* __restrict__ ws_cos)
{
    __shared__ float red[4];
    const int tid  = threadIdx.x;
    const int wave = tid >> 6, lane = tid & 63;

    // bijective XCD-contiguous swizzle (1280 % 8 == 0)
    const int bid = (int)blockIdx.x;
    const int swz = (bid & 7) * (NBLK / 8) + (bid >> 3);

    const int task  = swz * 2 + wave;
    const int img   = task / (NSEG * NSTRIP);
    const int rem   = task % (NSEG * NSTRIP);
    const int seg   = rem / NSTRIP;
    const int strip = rem - seg * NSTRIP;

    const int y0   = seg * SEGV;
    const int col0 = strip * STRIPW - 6 + lane * 2;      // even
    const int colc = min(max(col0, 0), WW - 2);
    const float mx = (col0 >= 0 && col0 < WW) ? 1.f : 0.f;
    const bool vout = (lane >= 3) && (lane <= 60) && (col0 < WW);

    const long base = (long)img * (CC * HW);

    // depth-2 pipeline: 3 rotating row buffers, 12 loads in flight
    float2 st[3][6];
#define LOADTO(S, Y) do { \
        const int yc_ = min(max((Y), 0), HH - 1); \
        const long off_ = base + (long)yc_ * WW + colc; \
        st[S][0] = *(const float2*)(pred + off_); \
        st[S][1] = *(const float2*)(pred + off_ + HW); \
        st[S][2] = *(const float2*)(pred + off_ + 2 * HW); \
        st[S][3] = *(const float2*)(target + off_); \
        st[S][4] = *(const float2*)(target + off_ + HW); \
        st[S][5] = *(const float2*)(target + off_ + 2 * HW); \
    } while (0)

    LOADTO(0, y0 - RAD + 0);
    LOADTO(1, y0 - RAD + 1);

    __half2 ring0[11], ring1[11], ringT[11];   // (hd0,hp0), (hd1,hp1), (ht0,ht1)
    float Sd0=0.f, Sd1=0.f, Sp0=0.f, Sp1=0.f, St0=0.f, St1=0.f;
    float sq = 0.f, cosacc = 0.f;

    #pragma unroll
    for (int it = 0; it < NITER; ++it) {
        const int s = it % 3;                      // static under unroll
        // issue prefetch for row it+2 FIRST (independent of this iter's math)
        if (it + 2 < NITER) LOADTO((it + 2) % 3, y0 - RAD + it + 2);

        const int y = y0 - RAD + it;
        const float msk = (y >= 0 && y < HH) ? mx : 0.f;

        const float2 p0 = st[s][0], p1 = st[s][1], p2 = st[s][2];
        const float2 t0 = st[s][3], t1 = st[s][4], t2 = st[s][5];

        // per-pixel dot/pp/tt, masked (zero padding outside image)
        const float ad = (p0.x*t0.x + p1.x*t1.x + p2.x*t2.x) * msk;
        const float bd = (p0.y*t0.y + p1.y*t1.y + p2.y*t2.y) * msk;
        const float ap = (p0.x*p0.x + p1.x*p1.x + p2.x*p2.x) * msk;
        const float bp = (p0.y*p0.y + p1.y*p1.y + p2.y*p2.y) * msk;
        const float at = (t0.x*t0.x + t1.x*t1.x + t2.x*t2.x) * msk;
        const float bt = (t0.y*t0.y + t1.y*t1.y + t2.y*t2.y) * msk;

        // PSNR squared error from the maps: sum_c (p-t)^2 = pp - 2*dot + tt
        if (it >= RAD && it < RAD + SEGV && vout) {
            sq += (ap + at - 2.f * ad) + (bp + bt - 2.f * bd);
        }

        // ---- horizontal 11-window ----
        __half2 h0dp, h1dp;
        {
            const __half2 Pk = __floats2half2_rn(ad + bd, ap + bp);
            const __half2 Ak = __floats2half2_rn(ad, ap);
            const __half2 Bk = __floats2half2_rn(bd, bp);
            const __half2 u1 = __hadd2(Pk, shfl_h2(Pk, lane + 1));
            const __half2 u2 = __hadd2(u1, shfl_h2(u1, lane + 2));
            const __half2 u3 = __hadd2(u2, shfl_h2(Pk, lane + 4));
            const __half2 S5 = shfl_h2(u3, lane - 2);
            h0dp = __hadd2(shfl_h2(Bk, lane - 3), S5);
            h1dp = __hadd2(S5, shfl_h2(Ak, lane + 3));
        }
        __half2 hT;
        {
            const float pr = at + bt;
            const float u1 = pr + __shfl(pr, lane + 1);
            const float u2 = u1 + __shfl(u1, lane + 2);
            const float u3 = u2 + __shfl(pr, lane + 4);
            const float S5 = __shfl(u3, lane - 2);
            hT = __floats2half2_rn(__shfl(bt, lane - 3) + S5,
                                   S5 + __shfl(at, lane + 3));
        }

        // accumulate the QUANTIZED values -> ring subtract cancels exactly
        const float2 f0 = __half22float2(h0dp);
        const float2 f1 = __half22float2(h1dp);
        const float2 fT = __half22float2(hT);
        Sd0 += f0.x; Sp0 += f0.y;
        Sd1 += f1.x; Sp1 += f1.y;
        St0 += fT.x; St1 += fT.y;

        if (it >= 10) {
            if (vout) {
                // d * rsqrt(pp*tt): eps-safe (windows have pp*tt >> 1e-6)
                cosacc += Sd0 * rsqrtf(fmaxf(Sp0 * St0, 1e-20f));
                cosacc += Sd1 * rsqrtf(fmaxf(Sp1 * St1, 1e-20f));
            }
            const float2 o0 = __half22float2(ring0[(it + 1) % 11]);
            const float2 o1 = __half22float2(ring1[(it + 1) % 11]);
            const float2 oT = __half22float2(ringT[(it + 1) % 11]);
            Sd0 -= o0.x; Sp0 -= o0.y;
            Sd1 -= o1.x; Sp1 -= o1.y;
            St0 -= oT.x; St1 -= oT.y;
        }
        ring0[it % 11] = h0dp;
        ring1[it % 11] = h1dp;
        ringT[it % 11] = hT;
    }

    // wave reduce -> block partials
    #pragma unroll
    for (int o = 32; o > 0; o >>= 1) {
        cosacc += __shfl_down(cosacc, o);
        sq     += __shfl_down(sq, o);
    }
    if (lane == 0) { red[wave] = cosacc; red[wave + 2] = sq; }
    __syncthreads();
    if (tid == 0) {
        ws_cos[swz] = red[0] + red[1];
        ws_sq [swz] = red[2] + red[3];
    }
}

// ---------------- finalize: 1280 sq + 1280 cos partials ----------------
__global__ __launch_bounds__(256) void finalize4(
    const float* __restrict__ ws_sq, const float* __restrict__ ws_cos,
    float* __restrict__ out)
{
    __shared__ float sq_b[16];
    __shared__ float cred[4];
    const int tid = threadIdx.x;

    // sq: 80 partials per image; 16 threads/image, 5 values each
    const int b = tid >> 4, j = tid & 15;
    float s = 0.f;
    #pragma unroll
    for (int k = 0; k < 5; ++k) s += ws_sq[b * 80 + j * 5 + k];
    #pragma unroll
    for (int o = 8; o > 0; o >>= 1) s += __shfl_down(s, o, 16);
    if (j == 0) sq_b[b] = s;

    float c = 0.f;
    #pragma unroll
    for (int k = 0; k < 5; ++k) c += ws_cos[tid + 256 * k];
    #pragma unroll
    for (int o = 32; o > 0; o >>= 1) c += __shfl_down(c, o);
    if ((tid & 63) == 0) cred[tid >> 6] = c;
    __syncthreads();

    if (tid == 0) {
        const float csum = cred[0] + cred[1] + cred[2] + cred[3];
        const float scale = 4.342944819032518f;   // 10 / ln(10)
        float lsum = 0.f;
        for (int bb = 0; bb < 16; ++bb)
            lsum += logf(sq_b[bb] / (float)(CC * HW) + 1e-8f);
        out[0] = scale * (lsum / (float)BB) + (1.f - csum / (float)(BB * HW));
    }
}

extern "C" void kernel_launch(void* const* d_in, const int* in_sizes, int n_in,
                              void* d_out, int out_size, void* d_ws, size_t ws_size,
                              hipStream_t stream)
{
    const float* pred   = (const float*)d_in[0];
    const float* target = (const float*)d_in[1];

    float* ws_sq  = (float*)d_ws;                        // 1280 floats
    float* ws_cos = (float*)((char*)d_ws + 8192);        // 1280 floats

    fused_shfl<<<dim3(NBLK), 128, 0, stream>>>(pred, target, ws_sq, ws_cos);
    finalize4<<<1, 256, 0, stream>>>(ws_sq, ws_cos, (float*)d_out);
}

// Round 12
// 36.316 us; speedup vs baseline: 1.2064x; 1.0014x over previous
//
#include <hip/hip_runtime.h>
#include <hip/hip_fp16.h>
#include <math.h>

#define BB 16
#define CC 3
#define HH 512
#define WW 512
#define HW (HH * WW)
#define RAD 5
#define SEGV 16
#define NSEG (HH / SEGV)            // 32 segments per image
#define NSTRIP 5                    // 5 overlapping 128-col strips, 116 valid each
#define STRIPW 116
#define NTASK (BB * NSEG * NSTRIP)  // 2560 wave-tasks
#define NBLK (NTASK / 2)            // 1280 blocks (2 waves each)
#define NITER (SEGV + 2 * RAD)      // 26 row iterations

__device__ __forceinline__ __half2 shfl_h2(__half2 v, int src) {
    union { __half2 h; int i; } u;
    u.h = v;
    u.i = __shfl(u.i, src);
    return u.h;
}

// R7 structure with a DEPTH-1 horizontal shuffle tree: S5 gathered via 4
// independent shuffles (+2 edge shuffles), summed by a short VALU tree --
// ~50 cyc critical path vs ~200 for the old 5-deep bpermute chain.
// Vertical: 11-deep half2 ring, exact-cancellation f32 running sums.
// No LDS/barriers in the main loop.
__global__ __launch_bounds__(128) void fused_shfl(
    const float* __restrict__ pred, const float* __restrict__ target,
    float* __restrict__ ws_sq, float* __restrict__ ws_cos)
{
    __shared__ float red[4];
    const int tid  = threadIdx.x;
    const int wave = tid >> 6, lane = tid & 63;

    // bijective XCD-contiguous swizzle (1280 % 8 == 0)
    const int bid = (int)blockIdx.x;
    const int swz = (bid & 7) * (NBLK / 8) + (bid >> 3);

    const int task  = swz * 2 + wave;
    const int img   = task / (NSEG * NSTRIP);
    const int rem   = task % (NSEG * NSTRIP);
    const int seg   = rem / NSTRIP;
    const int strip = rem - seg * NSTRIP;

    const int y0   = seg * SEGV;
    const int col0 = strip * STRIPW - 6 + lane * 2;      // even
    const int colc = min(max(col0, 0), WW - 2);
    const float mx = (col0 >= 0 && col0 < WW) ? 1.f : 0.f;
    const bool vout = (lane >= 3) && (lane <= 60) && (col0 < WW);

    const long base = (long)img * (CC * HW);

    // prefetch row 0 (issue-early), depth-1 (keeps VGPR ~68: R9/R11 lesson)
    float2 P0, P1, P2, T0, T1, T2;
    {
        const int y  = y0 - RAD;
        const int yc = y < 0 ? 0 : y;
        const long off = base + (long)yc * WW + colc;
        P0 = *(const float2*)(pred + off);
        P1 = *(const float2*)(pred + off + HW);
        P2 = *(const float2*)(pred + off + 2 * HW);
        T0 = *(const float2*)(target + off);
        T1 = *(const float2*)(target + off + HW);
        T2 = *(const float2*)(target + off + 2 * HW);
    }

    __half2 ring0[11], ring1[11], ringT[11];   // (hd0,hp0), (hd1,hp1), (ht0,ht1)
    float Sd0=0.f, Sd1=0.f, Sp0=0.f, Sp1=0.f, St0=0.f, St1=0.f;
    float sq = 0.f, cosacc = 0.f;

    #pragma unroll
    for (int it = 0; it < NITER; ++it) {
        const int y = y0 - RAD + it;
        const float msk = (y >= 0 && y < HH) ? mx : 0.f;

        const float2 p0=P0, p1=P1, p2=P2, t0=T0, t1=T1, t2=T2;
        if (it + 1 < NITER) {                     // prefetch next row
            const int y2  = y0 - RAD + it + 1;
            const int yc2 = min(max(y2, 0), HH - 1);
            const long off2 = base + (long)yc2 * WW + colc;
            P0 = *(const float2*)(pred + off2);
            P1 = *(const float2*)(pred + off2 + HW);
            P2 = *(const float2*)(pred + off2 + 2 * HW);
            T0 = *(const float2*)(target + off2);
            T1 = *(const float2*)(target + off2 + HW);
            T2 = *(const float2*)(target + off2 + 2 * HW);
        }

        // per-pixel dot/pp/tt, masked (zero padding outside image)
        const float ad = (p0.x*t0.x + p1.x*t1.x + p2.x*t2.x) * msk;
        const float bd = (p0.y*t0.y + p1.y*t1.y + p2.y*t2.y) * msk;
        const float ap = (p0.x*p0.x + p1.x*p1.x + p2.x*p2.x) * msk;
        const float bp = (p0.y*p0.y + p1.y*p1.y + p2.y*p2.y) * msk;
        const float at = (t0.x*t0.x + t1.x*t1.x + t2.x*t2.x) * msk;
        const float bt = (t0.y*t0.y + t1.y*t1.y + t2.y*t2.y) * msk;

        // PSNR squared error from the maps: sum_c (p-t)^2 = pp - 2*dot + tt
        if (it >= RAD && it < RAD + SEGV && vout) {
            sq += (ap + at - 2.f * ad) + (bp + bt - 2.f * bd);
        }

        // ---- horizontal 11-window, depth-1 shuffle fan ----
        // h(2i) = b_{i-3} + S5,  h(2i+1) = S5 + a_{i+3},
        // S5 = sum pr over lanes i-2..i+2 (pr = a+b pair sum)
        __half2 h0dp, h1dp;
        {
            const __half2 Pk = __floats2half2_rn(ad + bd, ap + bp);
            const __half2 Ak = __floats2half2_rn(ad, ap);
            const __half2 Bk = __floats2half2_rn(bd, bp);
            const __half2 xm2 = shfl_h2(Pk, lane - 2);
            const __half2 xm1 = shfl_h2(Pk, lane - 1);
            const __half2 xp1 = shfl_h2(Pk, lane + 1);
            const __half2 xp2 = shfl_h2(Pk, lane + 2);
            const __half2 eB  = shfl_h2(Bk, lane - 3);
            const __half2 eA  = shfl_h2(Ak, lane + 3);
            const __half2 S5  = __hadd2(__hadd2(__hadd2(Pk, xm1),
                                                __hadd2(xp1, xm2)), xp2);
            h0dp = __hadd2(eB, S5);
            h1dp = __hadd2(S5, eA);
        }
        __half2 hT;
        {
            const float pr  = at + bt;
            const float xm2 = __shfl(pr, lane - 2);
            const float xm1 = __shfl(pr, lane - 1);
            const float xp1 = __shfl(pr, lane + 1);
            const float xp2 = __shfl(pr, lane + 2);
            const float eB  = __shfl(bt, lane - 3);
            const float eA  = __shfl(at, lane + 3);
            const float S5  = ((pr + xm1) + (xp1 + xm2)) + xp2;
            hT = __floats2half2_rn(eB + S5, S5 + eA);
        }

        // accumulate the QUANTIZED values -> ring subtract cancels exactly
        const float2 f0 = __half22float2(h0dp);
        const float2 f1 = __half22float2(h1dp);
        const float2 fT = __half22float2(hT);
        Sd0 += f0.x; Sp0 += f0.y;
        Sd1 += f1.x; Sp1 += f1.y;
        St0 += fT.x; St1 += fT.y;

        if (it >= 10) {
            if (vout) {
                // d * rsqrt(pp*tt): eps-safe (windows have pp*tt >> 1e-6)
                cosacc += Sd0 * rsqrtf(fmaxf(Sp0 * St0, 1e-20f));
                cosacc += Sd1 * rsqrtf(fmaxf(Sp1 * St1, 1e-20f));
            }
            const float2 o0 = __half22float2(ring0[(it + 1) % 11]);
            const float2 o1 = __half22float2(ring1[(it + 1) % 11]);
            const float2 oT = __half22float2(ringT[(it + 1) % 11]);
            Sd0 -= o0.x; Sp0 -= o0.y;
            Sd1 -= o1.x; Sp1 -= o1.y;
            St0 -= oT.x; St1 -= oT.y;
        }
        ring0[it % 11] = h0dp;
        ring1[it % 11] = h1dp;
        ringT[it % 11] = hT;
    }

    // wave reduce -> block partials
    #pragma unroll
    for (int o = 32; o > 0; o >>= 1) {
        cosacc += __shfl_down(cosacc, o);
        sq     += __shfl_down(sq, o);
    }
    if (lane == 0) { red[wave] = cosacc; red[wave + 2] = sq; }
    __syncthreads();
    if (tid == 0) {
        ws_cos[swz] = red[0] + red[1];
        ws_sq [swz] = red[2] + red[3];
    }
}

// ---------------- finalize: 1280 sq + 1280 cos partials ----------------
__global__ __launch_bounds__(256) void finalize4(
    const float* __restrict__ ws_sq, const float* __restrict__ ws_cos,
    float* __restrict__ out)
{
    __shared__ float sq_b[16];
    __shared__ float cred[4];
    const int tid = threadIdx.x;

    // sq: 80 partials per image; 16 threads/image, 5 values each
    const int b = tid >> 4, j = tid & 15;
    float s = 0.f;
    #pragma unroll
    for (int k = 0; k < 5; ++k) s += ws_sq[b * 80 + j * 5 + k];
    #pragma unroll
    for (int o = 8; o > 0; o >>= 1) s += __shfl_down(s, o, 16);
    if (j == 0) sq_b[b] = s;

    float c = 0.f;
    #pragma unroll
    for (int k = 0; k < 5; ++k) c += ws_cos[tid + 256 * k];
    #pragma unroll
    for (int o = 32; o > 0; o >>= 1) c += __shfl_down(c, o);
    if ((tid & 63) == 0) cred[tid >> 6] = c;
    __syncthreads();

    if (tid == 0) {
        const float csum = cred[0] + cred[1] + cred[2] + cred[3];
        const float scale = 4.342944819032518f;   // 10 / ln(10)
        float lsum = 0.f;
        for (int bb = 0; bb < 16; ++bb)
            lsum += logf(sq_b[bb] / (float)(CC * HW) + 1e-8f);
        out[0] = scale * (lsum / (float)BB) + (1.f - csum / (float)(BB * HW));
    }
}

extern "C" void kernel_launch(void* const* d_in, const int* in_sizes, int n_in,
                              void* d_out, int out_size, void* d_ws, size_t ws_size,
                              hipStream_t stream)
{
    const float* pred   = (const float*)d_in[0];
    const float* target = (const float*)d_in[1];

    float* ws_sq  = (float*)d_ws;                        // 1280 floats
    float* ws_cos = (float*)((char*)d_ws + 8192);        // 1280 floats

    fused_shfl<<<dim3(NBLK), 128, 0, stream>>>(pred, target, ws_sq, ws_cos);
    finalize4<<<1, 256, 0, stream>>>(ws_sq, ws_cos, (float*)d_out);
}